// Round 8
// baseline (579.858 us; speedup 1.0000x reference)
//
#include <hip/hip_runtime.h>
#include <hip/hip_bf16.h>
#include <cstdint>
#include <cstddef>

#define NNODES 20000
#define MNB    16
#define NFEAT  500
#define OUTC   656

typedef short short8 __attribute__((ext_vector_type(8)));
typedef float floatx4 __attribute__((ext_vector_type(4)));

__device__ __forceinline__ float bf2f(unsigned int h) {
    union { unsigned int u; float f; } v; v.u = h << 16; return v.f;
}
__device__ __forceinline__ unsigned short f2bf(float f) {
    union { float f; unsigned int u; } v; v.f = f;
    unsigned int u = v.u;
    u += 0x7FFFu + ((u >> 16) & 1u);   // RNE
    return (unsigned short)(u >> 16);
}

// 16-lane (DPP-row) replicated sum.
template<int CTRL>
__device__ __forceinline__ float dpp_add(float v) {
    const int o = __builtin_amdgcn_update_dpp(0, __float_as_int(v), CTRL, 0xF, 0xF, true);
    return v + __int_as_float(o);
}
__device__ __forceinline__ float sum16(float v) {
    v = dpp_add<0xB1>(v);    // quad_perm xor1
    v = dpp_add<0x4E>(v);    // quad_perm xor2
    v = dpp_add<0x141>(v);   // row_half_mirror
    v = dpp_add<0x140>(v);   // row_mirror
    return v;
}

// ---------------- dtype probe
__global__ __launch_bounds__(64) void detect_kernel(const unsigned short* __restrict__ fx,
                                                    int* __restrict__ flag) {
    const int tid = threadIdx.x;
    const unsigned short s = fx[2 * tid];
    const int e = (s >> 7) & 0xFF;
    const bool ok = (e >= 100 && e <= 140);
    const unsigned long long m = __ballot(ok);
    if (tid == 0) *flag = (__popcll(m) >= 32) ? 1 : 0;
}

// ---------------- convert all weights/biases to one fp32 blob in ws
struct WPtrs { const void* p[12]; };

__global__ __launch_bounds__(256) void convert_weights(WPtrs ptrs, const int* __restrict__ flag,
                                                       float* __restrict__ outb) {
    constexpr int SN[12] = {64000,128,14336,112,10752,96,7680,80,5120,64,3072,48};
    constexpr int SO[12] = {0,64000,64128,78464,78576,89328,89424,97104,97184,102304,102368,105440};
    constexpr int TOT = 105488;
    const int i = blockIdx.x * 256 + threadIdx.x;
    if (i >= TOT) return;
    const bool isbf = (*flag != 0);
    int seg = 0, local = i;
#pragma unroll
    for (int s = 0; s < 12; ++s) {
        if (i >= SO[s] && i < SO[s] + SN[s]) { seg = s; local = i - SO[s]; }
    }
    const void* src = ptrs.p[seg];
    float v;
    if (isbf) v = bf2f(((const unsigned short*)src)[local]);
    else      v = ((const float*)src)[local];
    outb[i] = v;
}

// ---------------- pad pca_w (fp32 blob) -> bf16 [128][512] (K-padded with zeros)
__global__ __launch_bounds__(256) void convert_wpad(const float* __restrict__ wblob,
                                                    unsigned short* __restrict__ wpad) {
    const int i = blockIdx.x * 256 + threadIdx.x;   // 128*512 = 65536
    const int n = i >> 9, k = i & 511;
    const float v = (k < NFEAT) ? wblob[n * NFEAT + k] : 0.f;
    wpad[i] = f2bf(v);
}

// ---------------- PCA via MFMA (fp32 OR bf16 feature; inline bf16 conversion)
__global__ __launch_bounds__(256) void pca_mfma(
    const void* __restrict__ feat_raw,
    const unsigned short* __restrict__ wpad,   // [128][512] bf16
    const float* __restrict__ bias,
    const int* __restrict__ flag,
    float* __restrict__ xn,
    void* __restrict__ out_raw)
{
    __shared__ short sA[32 * 56];   // stride 56 shorts (112 B): 2-way banks = free
    __shared__ short sB[128 * 56];
    const int tid = threadIdx.x;
    const int l = tid & 63, wv = tid >> 6;
    const int m = l & 15, q = l >> 4;
    const int rt = wv >> 1, ch = wv & 1;       // row-tile, col-half
    const int r0 = blockIdx.x * 32;
    const bool isbf = (*flag != 0);

    const int arow = tid >> 3, aseg = tid & 7;

    floatx4 acc[4];
#pragma unroll
    for (int t = 0; t < 4; ++t) acc[t] = 0;

    for (int c = 0; c < 16; ++c) {
        const int k0 = c * 32;
        __syncthreads();
        {
            const int k = k0 + aseg * 4;
            uint2 v = make_uint2(0u, 0u);
            if (k < NFEAT) {
                if (isbf) {
                    v = *(const uint2*)((const unsigned short*)feat_raw +
                                        (size_t)(r0 + arow) * NFEAT + k);
                } else {
                    const float4 f = *(const float4*)((const float*)feat_raw +
                                                      (size_t)(r0 + arow) * NFEAT + k);
                    v.x = ((unsigned int)f2bf(f.y) << 16) | f2bf(f.x);
                    v.y = ((unsigned int)f2bf(f.w) << 16) | f2bf(f.z);
                }
            }
            *(uint2*)&sA[arow * 56 + aseg * 4] = v;
        }
#pragma unroll
        for (int it = 0; it < 4; ++it) {
            const int idx = tid + 256 * it;
            const int row = idx >> 3, seg = idx & 7;
            const uint2 v = *(const uint2*)(wpad + (size_t)row * 512 + k0 + seg * 4);
            *(uint2*)&sB[row * 56 + seg * 4] = v;
        }
        __syncthreads();
        const short8 af = *(const short8*)&sA[(rt * 16 + m) * 56 + q * 8];
#pragma unroll
        for (int t = 0; t < 4; ++t) {
            const short8 bf = *(const short8*)&sB[((ch * 4 + t) * 16 + m) * 56 + q * 8];
            acc[t] = __builtin_amdgcn_mfma_f32_16x16x32_bf16(af, bf, acc[t], 0, 0, 0);
        }
    }

#pragma unroll
    for (int t = 0; t < 4; ++t) {
        const int col = (ch * 4 + t) * 16 + m;
        const float bb = bias[col];
#pragma unroll
        for (int r = 0; r < 4; ++r) {
            const int grow = r0 + rt * 16 + q * 4 + r;
            const float y = fmaxf(acc[t][r] + bb, 0.f);
            if (isbf) ((unsigned short*)out_raw)[(size_t)grow * OUTC + col] = f2bf(y);
            else      ((float*)out_raw)[(size_t)grow * OUTC + col] = y;
            const float ss = sum16(y * y);
            const float invn = 1.0f / fmaxf(sqrtf(ss), 1e-12f);
            xn[(size_t)grow * 128 + col] = y * invn;
        }
    }
}

// ---------------- linear via MFMA, bf16x3 split precision (unchanged from round 7)
template<int FIN, int FOUT>
__global__ __launch_bounds__(256) void linear_mfma(
    const float* __restrict__ xin,
    const float* __restrict__ w,
    const float* __restrict__ bias,
    float* __restrict__ xn)
{
    constexpr int KP   = ((FIN + 31) / 32) * 32;
    constexpr int NCH  = KP / 32;
    constexpr int NTIL = 2 * (FOUT / 16);
    constexpr int MT   = (NTIL + 3) / 4;
    __shared__ short sAh[32 * 56], sAl[32 * 56];
    __shared__ short sBh[FOUT * 56], sBl[FOUT * 56];
    const int tid = threadIdx.x;
    const int l = tid & 63, wv = tid >> 6;
    const int m = l & 15, q = l >> 4;
    const int n0 = blockIdx.x * 32;

    floatx4 acc[MT];
#pragma unroll
    for (int i = 0; i < MT; ++i) acc[i] = 0;

    for (int c = 0; c < NCH; ++c) {
        const int k0 = c * 32;
        __syncthreads();
        {
            const int row = tid >> 3, seg = tid & 7;
            const int k = k0 + seg * 4;
            uint2 vh = make_uint2(0u, 0u), vl = make_uint2(0u, 0u);
            if (k < FIN) {
                const float4 f = *(const float4*)(xin + (size_t)(n0 + row) * FIN + k);
                const unsigned short h0 = f2bf(f.x), h1 = f2bf(f.y);
                const unsigned short h2 = f2bf(f.z), h3 = f2bf(f.w);
                const unsigned short e0 = f2bf(f.x - bf2f(h0)), e1 = f2bf(f.y - bf2f(h1));
                const unsigned short e2 = f2bf(f.z - bf2f(h2)), e3 = f2bf(f.w - bf2f(h3));
                vh = make_uint2(((unsigned)h1 << 16) | h0, ((unsigned)h3 << 16) | h2);
                vl = make_uint2(((unsigned)e1 << 16) | e0, ((unsigned)e3 << 16) | e2);
            }
            *(uint2*)&sAh[row * 56 + seg * 4] = vh;
            *(uint2*)&sAl[row * 56 + seg * 4] = vl;
        }
        for (int idx = tid; idx < FOUT * 8; idx += 256) {
            const int row = idx >> 3, seg = idx & 7;
            const int k = k0 + seg * 4;
            uint2 vh = make_uint2(0u, 0u), vl = make_uint2(0u, 0u);
            if (k < FIN) {
                const float4 f = *(const float4*)(w + (size_t)row * FIN + k);
                const unsigned short h0 = f2bf(f.x), h1 = f2bf(f.y);
                const unsigned short h2 = f2bf(f.z), h3 = f2bf(f.w);
                const unsigned short e0 = f2bf(f.x - bf2f(h0)), e1 = f2bf(f.y - bf2f(h1));
                const unsigned short e2 = f2bf(f.z - bf2f(h2)), e3 = f2bf(f.w - bf2f(h3));
                vh = make_uint2(((unsigned)h1 << 16) | h0, ((unsigned)h3 << 16) | h2);
                vl = make_uint2(((unsigned)e1 << 16) | e0, ((unsigned)e3 << 16) | e2);
            }
            *(uint2*)&sBh[row * 56 + seg * 4] = vh;
            *(uint2*)&sBl[row * 56 + seg * 4] = vl;
        }
        __syncthreads();
#pragma unroll
        for (int ti = 0; ti < MT; ++ti) {
            const int t = wv + ti * 4;
            if (t < NTIL) {
                const int rt = t & 1, ct = t >> 1;
                const int ao = (rt * 16 + m) * 56 + q * 8;
                const int bo = (ct * 16 + m) * 56 + q * 8;
                const short8 ah = *(const short8*)&sAh[ao];
                const short8 al = *(const short8*)&sAl[ao];
                const short8 bh = *(const short8*)&sBh[bo];
                const short8 bl = *(const short8*)&sBl[bo];
                floatx4 a = acc[ti];
                a = __builtin_amdgcn_mfma_f32_16x16x32_bf16(ah, bh, a, 0, 0, 0);
                a = __builtin_amdgcn_mfma_f32_16x16x32_bf16(ah, bl, a, 0, 0, 0);
                a = __builtin_amdgcn_mfma_f32_16x16x32_bf16(al, bh, a, 0, 0, 0);
                acc[ti] = a;
            }
        }
    }
#pragma unroll
    for (int ti = 0; ti < MT; ++ti) {
        const int t = wv + ti * 4;
        if (t < NTIL) {
            const int rt = t & 1, ct = t >> 1;
            const int col = ct * 16 + m;
            const float bb = bias[col];
#pragma unroll
            for (int r = 0; r < 4; ++r) {
                const int grow = n0 + rt * 16 + q * 4 + r;
                const float y = acc[ti][r] + bb;
                const float ss = sum16(y * y);
                const float invn = __builtin_amdgcn_rsqf(fmaxf(ss, 1e-24f));
                xn[(size_t)grow * FOUT + col] = y * invn;
            }
        }
    }
}

// ---------------- routing v4: scalar-array state, VGPR-resident via
// __launch_bounds__(256,4) (128-reg budget; v3's 56-VGPR alloc pushed the 96-float
// state into AGPRs -> accvgpr shuffling doubled the instruction count).
template<int K>
__global__ __launch_bounds__(256, 4) void routing4(
    const float* __restrict__ xn,
    const int* __restrict__ nb,
    float* __restrict__ xout,
    void* __restrict__ out_raw,
    const int* __restrict__ flag,
    const int coloff)
{
    constexpr int KD16 = K * 16;
    constexpr int NS = (K + 3) / 4;
    const int l = threadIdx.x & 63;
    const int wv = threadIdx.x >> 6;
    const int node = blockIdx.x * 4 + wv;
    const int j = l & 15, ks = l >> 4;
    const bool isbf = (*flag != 0);
    const int nid = nb[(size_t)node * 16 + j];

    float z[NS][16], u[NS][16], x16[NS][16];
    float invn[NS], vmul[NS];

#pragma unroll
    for (int i = 0; i < NS; ++i) {
        invn[i] = 1.0f;
        const bool full = (4 * i + 3 < K);                 // constexpr per unrolled i
        const bool valid = full || (ks + 4 * i < K);
        vmul[i] = valid ? 1.0f : 0.0f;
        const int kk = ks + 4 * i;
        const int kkc = full ? kk : (valid ? kk : (K - 1)); // clamp: no garbage/NaN
        const float* zsrc = xn + (size_t)nid  * KD16 + kkc * 16;
        const float* xsrc = xn + (size_t)node * KD16 + kkc * 16;
#pragma unroll
        for (int q = 0; q < 4; ++q) {
            const float4 zq = *(const float4*)(zsrc + q * 4);
            const float4 xq = *(const float4*)(xsrc + q * 4);
            z[i][q*4+0] = zq.x; z[i][q*4+1] = zq.y; z[i][q*4+2] = zq.z; z[i][q*4+3] = zq.w;
            u[i][q*4+0] = xq.x; u[i][q*4+1] = xq.y; u[i][q*4+2] = xq.z; u[i][q*4+3] = xq.w;
            x16[i][q*4+0] = xq.x * 0.0625f; x16[i][q*4+1] = xq.y * 0.0625f;
            x16[i][q*4+2] = xq.z * 0.0625f; x16[i][q*4+3] = xq.w * 0.0625f;
        }
    }

    for (int t = 0; t < 5; ++t) {
        float e[NS], s = 0.f;
#pragma unroll
        for (int i = 0; i < NS; ++i) {
            // 2-way split dot for ILP
            float pa = z[i][0] * u[i][0], pb = z[i][8] * u[i][8];
#pragma unroll
            for (int d = 1; d < 8; ++d) {
                pa = fmaf(z[i][d],     u[i][d],     pa);
                pb = fmaf(z[i][d + 8], u[i][d + 8], pb);
            }
            e[i] = __expf((pa + pb) * invn[i]) * vmul[i];
            s += e[i];
        }
        s += __shfl_xor(s, 16);
        s += __shfl_xor(s, 32);
        const float sc = __builtin_amdgcn_rcpf(s);
#pragma unroll
        for (int i = 0; i < NS; ++i) {
            const float ei = e[i] * sc;
#pragma unroll
            for (int d = 0; d < 16; ++d)
                u[i][d] = sum16(fmaf(ei, z[i][d], x16[i][d]));
        }
        if (t < 4) {
#pragma unroll
            for (int i = 0; i < NS; ++i) {
                float sa = u[i][0] * u[i][0], sb = u[i][8] * u[i][8];
#pragma unroll
                for (int d = 1; d < 8; ++d) {
                    sa = fmaf(u[i][d],     u[i][d],     sa);
                    sb = fmaf(u[i][d + 8], u[i][d + 8], sb);
                }
                invn[i] = __builtin_amdgcn_rsqf(fmaxf(sa + sb, 1e-24f));
            }
        }
    }

#pragma unroll
    for (int i = 0; i < NS; ++i)
#pragma unroll
        for (int d = 0; d < 16; ++d) u[i][d] = fmaxf(u[i][d], 0.f);

    if (j < 4) {
#pragma unroll
        for (int i = 0; i < NS; ++i) {
            const int kk = ks + 4 * i;
            if (kk < K) {
                float4 w4 = make_float4(u[i][0], u[i][1], u[i][2], u[i][3]);
                if (j == 1) w4 = make_float4(u[i][4],  u[i][5],  u[i][6],  u[i][7]);
                else if (j == 2) w4 = make_float4(u[i][8],  u[i][9],  u[i][10], u[i][11]);
                else if (j == 3) w4 = make_float4(u[i][12], u[i][13], u[i][14], u[i][15]);
                *(float4*)(xout + (size_t)node * KD16 + kk * 16 + j * 4) = w4;
                const size_t ooff = (size_t)node * OUTC + coloff + kk * 16 + j * 4;
                if (isbf) {
                    uint2 pk;
                    pk.x = ((unsigned int)f2bf(w4.y) << 16) | f2bf(w4.x);
                    pk.y = ((unsigned int)f2bf(w4.w) << 16) | f2bf(w4.z);
                    *(uint2*)((unsigned short*)out_raw + ooff) = pk;
                } else {
                    *(float4*)((float*)out_raw + ooff) = w4;
                }
            }
        }
    }
}

extern "C" void kernel_launch(void* const* d_in, const int* in_sizes, int n_in,
                              void* d_out, int out_size, void* d_ws, size_t ws_size,
                              hipStream_t stream) {
    const int* nbid = (const int*)d_in[1];

    int*            flag  = (int*)d_ws;
    float*          wblob = (float*)((char*)d_ws + 16);
    unsigned short* wpad  = (unsigned short*)((char*)d_ws + (448 << 10));
    float*          xn    = (float*)((char*)d_ws + (1 << 20));
    float*          xc    = xn + (size_t)NNODES * 128;

    float* pw = wblob +      0; float* pb = wblob +  64000;
    float* w1 = wblob +  64128; float* b1 = wblob +  78464;
    float* w2 = wblob +  78576; float* b2 = wblob +  89328;
    float* w3 = wblob +  89424; float* b3 = wblob +  97104;
    float* w4 = wblob +  97184; float* b4 = wblob + 102304;
    float* w5 = wblob + 102368; float* b5 = wblob + 105440;

    hipLaunchKernelGGL(detect_kernel, dim3(1), dim3(64), 0, stream,
                       (const unsigned short*)d_in[0], flag);

    WPtrs wp;
    for (int i = 0; i < 12; ++i) wp.p[i] = d_in[i + 2];
    hipLaunchKernelGGL(convert_weights, dim3(413), dim3(256), 0, stream, wp, flag, wblob);
    hipLaunchKernelGGL(convert_wpad, dim3(256), dim3(256), 0, stream, pw, wpad);

    hipLaunchKernelGGL(pca_mfma, dim3(NNODES / 32), dim3(256), 0, stream,
                       d_in[0], wpad, pb, flag, xn, d_out);

    const int rgrid = NNODES / 4;
    const int lgrid = NNODES / 32;

    hipLaunchKernelGGL((routing4<8>), dim3(rgrid), dim3(256), 0, stream,
                       xn, nbid, xc, d_out, flag, 128);
    hipLaunchKernelGGL((linear_mfma<128, 112>), dim3(lgrid), dim3(256), 0, stream,
                       xc, w1, b1, xn);

    hipLaunchKernelGGL((routing4<7>), dim3(rgrid), dim3(256), 0, stream,
                       xn, nbid, xc, d_out, flag, 256);
    hipLaunchKernelGGL((linear_mfma<112, 96>), dim3(lgrid), dim3(256), 0, stream,
                       xc, w2, b2, xn);

    hipLaunchKernelGGL((routing4<6>), dim3(rgrid), dim3(256), 0, stream,
                       xn, nbid, xc, d_out, flag, 368);
    hipLaunchKernelGGL((linear_mfma<96, 80>), dim3(lgrid), dim3(256), 0, stream,
                       xc, w3, b3, xn);

    hipLaunchKernelGGL((routing4<5>), dim3(rgrid), dim3(256), 0, stream,
                       xn, nbid, xc, d_out, flag, 464);
    hipLaunchKernelGGL((linear_mfma<80, 64>), dim3(lgrid), dim3(256), 0, stream,
                       xc, w4, b4, xn);

    hipLaunchKernelGGL((routing4<4>), dim3(rgrid), dim3(256), 0, stream,
                       xn, nbid, xc, d_out, flag, 544);
    hipLaunchKernelGGL((linear_mfma<64, 48>), dim3(lgrid), dim3(256), 0, stream,
                       xc, w5, b5, xn);

    hipLaunchKernelGGL((routing4<3>), dim3(rgrid), dim3(256), 0, stream,
                       xn, nbid, xc, d_out, flag, 608);
}